// Round 6
// baseline (12841.470 us; speedup 1.0000x reference)
//
#include <hip/hip_runtime.h>

#define Bb 128
#define Tt 512
#define Vv 96
#define Hh 512
#define OUT_H 6291456
#define OUT_C 6488064

typedef _Float16 f16x4 __attribute__((ext_vector_type(4)));
typedef _Float16 f16x8 __attribute__((ext_vector_type(8)));
typedef float f32x4 __attribute__((ext_vector_type(4)));

struct KP {
  const float *x, *h0, *c0;
  const float *Wih0, *Whh0, *bih0, *bhh0;
  const float *Wih1, *Whh1, *bih1, *bhh1;
  const float *Wih2, *Whh2, *bih2, *bhh2;
  const float *Wfc, *bfc;
  float* out;
  unsigned* flags;   // flags[bid] at flags[bid*32]: #completed steps; single writer
  float* fbias;      // [3][2048] fused gate biases + [96] fc bias
  _Float16* wimg;    // [98][65536] per-block pre-swizzled LDS images
  _Float16* xb;      // [Bb][Tt][Vv] f16 input
  _Float16* hring;   // [3][8][Bb][Hh] f16 h ring, depth 8; h0 in slot 7
};

__device__ __forceinline__ float sigf(float x) { return 1.f / (1.f + __expf(-x)); }

// Device-coherent (MALL, sc1) relaxed accessors — no wbl2/inv cache maintenance.
__device__ __forceinline__ f16x4 ld_dc_f16x4(const _Float16* p) {
  unsigned long long u = __hip_atomic_load((const unsigned long long*)p, __ATOMIC_RELAXED, __HIP_MEMORY_SCOPE_AGENT);
  union { unsigned long long u; f16x4 f; } c; c.u = u; return c.f;
}
__device__ __forceinline__ void st_dc_u32(unsigned* p, unsigned v) {
  __hip_atomic_store(p, v, __ATOMIC_RELAXED, __HIP_MEMORY_SCOPE_AGENT);
}

// Wave-parallel group wait (executed by wave 0 only): lane i polls flag gbase+(i&mask);
// one vector load per round covers the whole group. Single-writer flags -> no RMW.
__device__ __forceinline__ void wait_group(unsigned* flags, int gbase, int mask, unsigned target) {
  const int lane = threadIdx.x & 63;
  unsigned* p = &flags[(gbase + (lane & mask)) * 32];
  int guard = 0;
  for (;;) {
    unsigned v = __hip_atomic_load(p, __ATOMIC_RELAXED, __HIP_MEMORY_SCOPE_AGENT);
    if (__all((int)(v >= target))) break;
    if (++guard > 30000) break;   // broken pipeline terminates; absmax diagnoses
    __builtin_amdgcn_s_sleep(2);
  }
}

// acc += A[128 x 16K] * W^T from LDS. 8 waves split M (wave w: rows w*16..+15).
// ALL KSTEPS A-fragments issued upfront (<=32 loads, 64 VGPR) -> one latency stall.
template <int KSTEPS, int LSTRIDE, bool SWZ, int NF, bool DC>
__device__ __forceinline__ void gemm1(const _Float16* __restrict__ Abase, int astride,
                                      const _Float16* lds, f32x4 (&acc)[NF]) {
  const int lane = threadIdx.x & 63;
  const int w = threadIdx.x >> 6;
  const int l15 = lane & 15, l4 = lane >> 4;
  const _Float16* ap = Abase + (w * 16 + l15) * astride + l4 * 4;
  f16x4 av[KSTEPS];
#pragma unroll
  for (int i = 0; i < KSTEPS; ++i) {
    const _Float16* p = ap + i * 16;
    av[i] = DC ? ld_dc_f16x4(p) : *(const f16x4*)p;
  }
#pragma unroll
  for (int i = 0; i < KSTEPS; ++i) {
    const int kk = i * 16;
#pragma unroll
    for (int n = 0; n < NF; ++n) {
      const int r = n * 16 + l15;
      int idx = r * LSTRIDE + kk + l4 * 4;
      if (SWZ) idx ^= (r & 7) << 3;
      f16x4 bv = *(const f16x4*)(lds + idx);
      acc[n] = __builtin_amdgcn_mfma_f32_16x16x16f16(av[i], bv, acc[n], 0, 0, 0);
    }
  }
}

// Fused dual-GEMM: acc += A1*B1^T + A2*B2^T. All 64 sc1 A-loads issued upfront
// (128 VGPR in flight; 128KB-LDS blocks are 1/CU so up to 256 VGPR is free).
template <int NF>
__device__ __forceinline__ void gemm2(const _Float16* __restrict__ A1,
                                      const _Float16* __restrict__ A2,
                                      const _Float16* lds1, const _Float16* lds2,
                                      f32x4 (&acc)[NF]) {
  const int lane = threadIdx.x & 63;
  const int w = threadIdx.x >> 6;
  const int l15 = lane & 15, l4 = lane >> 4;
  const _Float16* ap1 = A1 + (w * 16 + l15) * 512 + l4 * 4;
  const _Float16* ap2 = A2 + (w * 16 + l15) * 512 + l4 * 4;
  f16x4 av1[32], av2[32];
#pragma unroll
  for (int i = 0; i < 32; ++i) av1[i] = ld_dc_f16x4(ap1 + i * 16);
#pragma unroll
  for (int i = 0; i < 32; ++i) av2[i] = ld_dc_f16x4(ap2 + i * 16);
#pragma unroll
  for (int i = 0; i < 32; ++i) {
    const int kk = i * 16;
#pragma unroll
    for (int n = 0; n < NF; ++n) {
      const int r = n * 16 + l15;
      int idx = (r * 512 + kk + l4 * 4) ^ ((r & 7) << 3);
      f16x4 b1 = *(const f16x4*)(lds1 + idx);
      acc[n] = __builtin_amdgcn_mfma_f32_16x16x16f16(av1[i], b1, acc[n], 0, 0, 0);
    }
  }
#pragma unroll
  for (int i = 0; i < 32; ++i) {
    const int kk = i * 16;
#pragma unroll
    for (int n = 0; n < NF; ++n) {
      const int r = n * 16 + l15;
      int idx = (r * 512 + kk + l4 * 4) ^ ((r & 7) << 3);
      f16x4 b2 = *(const f16x4*)(lds2 + idx);
      acc[n] = __builtin_amdgcn_mfma_f32_16x16x16f16(av2[i], b2, acc[n], 0, 0, 0);
    }
  }
}

__global__ __launch_bounds__(256) void prologue_kernel(KP A) {
  const int tid = threadIdx.x, bid = blockIdx.x;
  const int gt = bid * 256 + tid, gn = 98 * 256;
  for (int i = gt; i < Bb * Tt * Vv; i += gn) A.xb[i] = (_Float16)A.x[i];
  for (int i = gt; i < 3 * Bb * Hh; i += gn) {
    int l = i >> 16, rem = i & 65535;
    A.hring[(l * 8 + 7) * (Bb * Hh) + rem] = (_Float16)A.h0[i];
  }
  for (int i = gt; i < 3 * 2048; i += gn) {
    int l = i >> 11, c = i & 2047;
    const float* bi = (l == 0) ? A.bih0 : (l == 1) ? A.bih1 : A.bih2;
    const float* bh = (l == 0) ? A.bhh0 : (l == 1) ? A.bhh1 : A.bhh2;
    A.fbias[i] = bi[c] + bh[c];
  }
  for (int i = gt; i < Vv; i += gn) A.fbias[3 * 2048 + i] = A.bfc[i];

  _Float16* img = A.wimg + (size_t)bid * 65536;
  if (bid < 96) {
    const int l = bid >> 5, j0 = (bid & 31) * 16;
    const float* Wh = (l == 0) ? A.Whh0 : (l == 1) ? A.Whh1 : A.Whh2;
    for (int e = tid; e < 64 * 512; e += 256) {   // W_hh slice, rows = gate*16+col
      int r = e >> 9, k = e & 511;
      img[(r * 512 + k) ^ ((r & 7) << 3)] = (_Float16)Wh[((r >> 4) * 512 + j0 + (r & 15)) * Hh + k];
    }
    if (l == 0) {
      for (int e = tid; e < 64 * 96; e += 256) {
        int r = e / 96, k = e - r * 96;
        img[32768 + r * 104 + k] = (_Float16)A.Wih0[((r >> 4) * 512 + j0 + (r & 15)) * Vv + k];
      }
    } else {
      const float* Wi = (l == 1) ? A.Wih1 : A.Wih2;
      for (int e = tid; e < 64 * 512; e += 256) {
        int r = e >> 9, k = e & 511;
        img[32768 + ((r * 512 + k) ^ ((r & 7) << 3))] = (_Float16)Wi[((r >> 4) * 512 + j0 + (r & 15)) * Hh + k];
      }
    }
  } else {
    const int nt = bid - 96;
    for (int e = tid; e < 48 * 512; e += 256) {
      int r = e >> 9, k = e & 511;
      img[(r * 512 + k) ^ ((r & 7) << 3)] = (_Float16)A.Wfc[(nt * 48 + r) * Hh + k];
    }
  }
}

__global__ __launch_bounds__(512) void lstm_persist(KP A) {
  __shared__ _Float16 wlds[65536];  // 128 KB: [0..32768) W_hh/W_fc, [32768..) W_ih
  const int tid = threadIdx.x, bid = blockIdx.x;
  const int lane = tid & 63, w = tid >> 6;
  const int l15 = lane & 15, l4 = lane >> 4;
  unsigned* flags = A.flags;

  const bool isfc = (bid >= 96);
  const int l = isfc ? 2 : (bid >> 5);
  const int j0 = isfc ? 0 : (bid & 31) * 16;
  const int nt = isfc ? bid - 96 : 0;

  {  // stage pre-swizzled weight image ONCE
    const f16x8* src = (const f16x8*)(A.wimg + (size_t)bid * 65536);
    f16x8* dst = (f16x8*)wlds;
    const int cnt = isfc ? 3072 : 8192;
    for (int e = tid; e < cnt; e += 512) dst[e] = src[e];
  }

  if (!isfc) {
    float biasr[4], creg[4];
#pragma unroll
    for (int n = 0; n < 4; ++n) biasr[n] = A.fbias[l * 2048 + n * 512 + j0 + l15];
#pragma unroll
    for (int q = 0; q < 4; ++q)
      creg[q] = A.c0[l * (Bb * Hh) + (w * 16 + l4 * 4 + q) * Hh + j0 + l15];
    __syncthreads();

    for (int t = 0; t < Tt; ++t) {
      if (tid < 64) {
        if (t > 0) wait_group(flags, l * 32, 31, (unsigned)t);             // own h(t-1)
        if (l > 0) wait_group(flags, (l - 1) * 32, 31, (unsigned)(t + 1)); // producer h_{l-1}(t)
        if (t >= 8) {                                                      // ring overwrite guard
          if (l < 2) wait_group(flags, (l + 1) * 32, 31, (unsigned)(t - 7));
          else       wait_group(flags, 96, 1, (unsigned)(t - 7));
        }
      }
      __syncthreads();

      f32x4 acc[4] = {};
      const _Float16* hprev = A.hring + (size_t)(l * 8 + ((t - 1) & 7)) * (Bb * Hh);
      if (l == 0) {
        gemm1<6, 104, false, 4, false>(A.xb + t * Vv, Tt * Vv, wlds + 32768, acc);
        gemm1<32, 512, true, 4, true>(hprev, Hh, wlds, acc);
      } else {
        const _Float16* hin = A.hring + (size_t)((l - 1) * 8 + (t & 7)) * (Bb * Hh);
        gemm2<4>(hin, hprev, wlds + 32768, wlds, acc);
      }

      _Float16* rp = A.hring + (size_t)(l * 8 + (t & 7)) * (Bb * Hh);
      const int j = j0 + l15;
#pragma unroll
      for (int q = 0; q < 4; ++q) {
        const int b = w * 16 + l4 * 4 + q;
        float gi = acc[0][q] + biasr[0];
        float gf = acc[1][q] + biasr[1];
        float gg = acc[2][q] + biasr[2];
        float go = acc[3][q] + biasr[3];
        float iv = sigf(gi), fv = sigf(gf), gv = tanhf(gg), ov = sigf(go);
        float cn = fv * creg[q] + iv * gv;
        creg[q] = cn;
        float hv = ov * tanhf(cn);
        union { _Float16 h; unsigned short u; } cv; cv.h = (_Float16)hv;
        unsigned hb = cv.u;
        unsigned ob = (unsigned)__shfl_xor((int)hb, 1, 64);
        if ((l15 & 1) == 0) st_dc_u32((unsigned*)(rp + b * Hh + j), hb | (ob << 16));
        if (t == Tt - 1) {
          A.out[OUT_H + (l * Bb + b) * Hh + j] = hv;
          A.out[OUT_C + (l * Bb + b) * Hh + j] = cn;
        }
      }
      __syncthreads();   // drain vmcnt: all sc1 stores at MALL before flag publish
      if (tid == 0) st_dc_u32(&flags[bid * 32], (unsigned)(t + 1));
    }
  } else {
    float biasr[3];
#pragma unroll
    for (int n = 0; n < 3; ++n) biasr[n] = A.fbias[3 * 2048 + nt * 48 + n * 16 + l15];
    __syncthreads();

    for (int t = 0; t < Tt; ++t) {
      if (tid < 64) wait_group(flags, 64, 31, (unsigned)(t + 1));   // h_2(t) ready
      __syncthreads();
      f32x4 acc[3] = {};
      gemm1<32, 512, true, 3, true>(A.hring + (size_t)(16 + (t & 7)) * (Bb * Hh), Hh, wlds, acc);
#pragma unroll
      for (int n = 0; n < 3; ++n)
#pragma unroll
        for (int q = 0; q < 4; ++q) {
          int b = w * 16 + l4 * 4 + q;
          A.out[(b * Tt + t) * Vv + nt * 48 + n * 16 + l15] = acc[n][q] + biasr[n];
        }
      __syncthreads();
      if (tid == 0) st_dc_u32(&flags[bid * 32], (unsigned)(t + 1));
    }
  }
}

extern "C" void kernel_launch(void* const* d_in, const int* in_sizes, int n_in,
                              void* d_out, int out_size, void* d_ws, size_t ws_size,
                              hipStream_t stream) {
  char* base = (char*)d_ws;
  KP a;
  a.x    = (const float*)d_in[0];
  a.h0   = (const float*)d_in[1];
  a.c0   = (const float*)d_in[2];
  a.Wih0 = (const float*)d_in[3];  a.Whh0 = (const float*)d_in[4];
  a.bih0 = (const float*)d_in[5];  a.bhh0 = (const float*)d_in[6];
  a.Wih1 = (const float*)d_in[7];  a.Whh1 = (const float*)d_in[8];
  a.bih1 = (const float*)d_in[9];  a.bhh1 = (const float*)d_in[10];
  a.Wih2 = (const float*)d_in[11]; a.Whh2 = (const float*)d_in[12];
  a.bih2 = (const float*)d_in[13]; a.bhh2 = (const float*)d_in[14];
  a.Wfc  = (const float*)d_in[15]; a.bfc  = (const float*)d_in[16];
  a.out  = (float*)d_out;
  a.flags = (unsigned*)base;                    // 16 KB (98 flags, 128B apart)
  a.fbias = (float*)(base + 16384);             // 24,960 B used
  a.wimg  = (_Float16*)(base + 49152);          // 12,845,056 B
  a.xb    = (_Float16*)(base + 12894208);       // 12,582,912 B
  a.hring = (_Float16*)(base + 25477120);       // 3,145,728 B  (total ~28.6 MB)

  hipMemsetAsync(a.flags, 0, 16384, stream);
  hipLaunchKernelGGL(prologue_kernel, dim3(98), dim3(256), 0, stream, a);
  hipLaunchKernelGGL(lstm_persist, dim3(98), dim3(512), 0, stream, a);
}

// Round 7
// 6894.585 us; speedup vs baseline: 1.8625x; 1.8625x over previous
//
#include <hip/hip_runtime.h>

#define Bb 128
#define Tt 512
#define Vv 96
#define Hh 512
#define OUT_H 6291456
#define OUT_C 6488064

typedef _Float16 f16x4 __attribute__((ext_vector_type(4)));
typedef _Float16 f16x8 __attribute__((ext_vector_type(8)));
typedef float f32x4 __attribute__((ext_vector_type(4)));

struct KP {
  const float *x, *h0, *c0;
  const float *Wih0, *Whh0, *bih0, *bhh0;
  const float *Wih1, *Whh1, *bih1, *bhh1;
  const float *Wih2, *Whh2, *bih2, *bhh2;
  const float *Wfc, *bfc;
  float* out;
  unsigned* flags;   // [7 groups][32 words] packed: 1 cacheline per subgroup
  float* fbias;      // [3][2048] gate biases + [96] fc bias
  _Float16* wimg;    // [96][65536] cell weight images (W_hh | W_ih), pre-swizzled
  _Float16* wfc;     // [49152] FC weight image, pre-swizzled
  _Float16* xb;      // [128][512][96] f16 input
  _Float16* hbuf;    // [6 grp][8 slots][64][512] f16 h ring
};

__device__ __forceinline__ float sigf(float x) { return 1.f / (1.f + __expf(-x)); }

__device__ __forceinline__ f16x4 ld_dc_f16x4(const _Float16* p) {
  unsigned long long u = __hip_atomic_load((const unsigned long long*)p, __ATOMIC_RELAXED, __HIP_MEMORY_SCOPE_AGENT);
  union { unsigned long long u; f16x4 f; } c; c.u = u; return c.f;
}
__device__ __forceinline__ void st_dc_u32(unsigned* p, unsigned v) {
  __hip_atomic_store(p, v, __ATOMIC_RELAXED, __HIP_MEMORY_SCOPE_AGENT);
}

// Dual wait: lane-private (word,target) pairs, both sets polled in one loop.
__device__ __forceinline__ void wait2(unsigned* flags, int w1, int t1, int w2, int t2) {
  unsigned* p1 = flags + w1;
  unsigned* p2 = flags + w2;
  int g = 0;
  for (;;) {
    int v1 = (int)__hip_atomic_load(p1, __ATOMIC_RELAXED, __HIP_MEMORY_SCOPE_AGENT);
    int v2 = (int)__hip_atomic_load(p2, __ATOMIC_RELAXED, __HIP_MEMORY_SCOPE_AGENT);
    if (__all(v1 >= t1 && v2 >= t2)) break;
    if (++g > 30000) break;   // deadlock terminates; absmax diagnoses
    __builtin_amdgcn_s_sleep(2);
  }
}

template <int KS>
__device__ __forceinline__ void load_dc(const _Float16* p, f16x4 (&av)[KS]) {
#pragma unroll
  for (int i = 0; i < KS; ++i) av[i] = ld_dc_f16x4(p + i * 16);
}

// acc += av (KS k-steps from k-base kb) * W^T from swizzled LDS [NF*16 rows][512].
template <int KS, int NF>
__device__ __forceinline__ void mma_swz(const f16x4 (&av)[KS], const _Float16* ldsb,
                                        int kb, int l15, int l4, f32x4 (&acc)[NF]) {
#pragma unroll
  for (int i = 0; i < KS; ++i) {
#pragma unroll
    for (int n = 0; n < NF; ++n) {
      const int gr = n * 16 + l15;
      const int idx = ((gr << 9) + kb + i * 16 + (l4 << 2)) ^ ((gr & 7) << 3);
      f16x4 bv = *(const f16x4*)(ldsb + idx);
      acc[n] = __builtin_amdgcn_mfma_f32_16x16x16f16(av[i], bv, acc[n], 0, 0, 0);
    }
  }
}

__global__ __launch_bounds__(256) void prologue_kernel(KP A) {
  const int tid = threadIdx.x, bid = blockIdx.x;
  const int gt = bid * 256 + tid, gn = 98 * 256;
  for (int i = gt; i < Bb * Tt * Vv; i += gn) A.xb[i] = (_Float16)A.x[i];
  // h0 -> hbuf slot 7 of each (l,half)
  for (int i = gt; i < 3 * Bb * Hh; i += gn) {
    int l = i >> 16, b = (i >> 9) & 127, col = i & 511;
    int half = b >> 6, bl = b & 63;
    A.hbuf[(size_t)((l * 2 + half) * 8 + 7) * 32768 + bl * 512 + col] = (_Float16)A.h0[i];
  }
  for (int i = gt; i < 3 * 2048; i += gn) {
    int l = i >> 11, cc = i & 2047;
    const float* bi = (l == 0) ? A.bih0 : (l == 1) ? A.bih1 : A.bih2;
    const float* bh = (l == 0) ? A.bhh0 : (l == 1) ? A.bhh1 : A.bhh2;
    A.fbias[i] = bi[cc] + bh[cc];
  }
  for (int i = gt; i < Vv; i += gn) A.fbias[3 * 2048 + i] = A.bfc[i];

  if (bid < 96) {
    const int l = bid >> 5, c = bid & 31;
    _Float16* img = A.wimg + (size_t)bid * 65536;
    const float* Wh = (l == 0) ? A.Whh0 : (l == 1) ? A.Whh1 : A.Whh2;
    for (int e = tid; e < 64 * 512; e += 256) {   // W_hh slice rows r = g*16+jj
      int r = e >> 9, k = e & 511;
      float v = Wh[((r >> 4) * 512 + c * 16 + (r & 15)) * Hh + k];
      img[(r * 512 + k) ^ ((r & 7) << 3)] = (_Float16)v;
    }
    if (l == 0) {
      for (int e = tid; e < 64 * 96; e += 256) {  // W_ih0 [64][112] padded, linear
        int r = e / 96, k = e - r * 96;
        img[32768 + r * 112 + k] = (_Float16)A.Wih0[((r >> 4) * 512 + c * 16 + (r & 15)) * Vv + k];
      }
    } else {
      const float* Wi = (l == 1) ? A.Wih1 : A.Wih2;
      for (int e = tid; e < 64 * 512; e += 256) {
        int r = e >> 9, k = e & 511;
        float v = Wi[((r >> 4) * 512 + c * 16 + (r & 15)) * Hh + k];
        img[32768 + ((r * 512 + k) ^ ((r & 7) << 3))] = (_Float16)v;
      }
    }
  } else {   // bid 96/97: FC image halves
    const int r0 = (bid - 96) * 48;
    for (int e = tid; e < 48 * 512; e += 256) {
      int r = r0 + (e >> 9), k = e & 511;
      A.wfc[(r * 512 + k) ^ ((r & 7) << 3)] = (_Float16)A.Wfc[r * 512 + k];
    }
  }
}

__global__ __launch_bounds__(512, 2) void lstm_persist(KP A) {
  __shared__ _Float16 wlds[65536];   // 128 KB weights
  __shared__ float redx[6144];       // 24 KB k-split reduction scratch
  const int tid = threadIdx.x, bid = blockIdx.x;
  const int lane = tid & 63, w = tid >> 6;
  const int l15 = lane & 15, l4 = lane >> 4;
  const int mf = w & 3, kh = w >> 2;
  unsigned* flags = A.flags;

  const bool isfc = (bid >= 192);
  const int l = isfc ? 2 : (bid >> 6);
  const int half = isfc ? (bid - 192) : ((bid >> 5) & 1);
  const int c = isfc ? 0 : (bid & 31);
  const int grp = isfc ? 6 : (l * 2 + half);

  {  // stage pre-swizzled weights once
    const f16x8* src = isfc ? (const f16x8*)A.wfc
                            : (const f16x8*)(A.wimg + (size_t)(l * 32 + c) * 65536);
    f16x8* dst = (f16x8*)wlds;
    const int cnt = isfc ? 6144 : 8192;
    for (int e = tid; e < cnt; e += 512) dst[e] = src[e];
  }

  // wait-set wiring: lane-private (word, target-offset) pairs
  int w1, w2, off1, off2;
  if (!isfc) {
    w1 = grp * 32 + (lane & 31); off1 = 0;                       // own subgroup >= t
    if (lane < 32) {
      if (l > 0) { w2 = (grp - 2) * 32 + lane; off2 = 1; }       // producer >= t+1
      else       { w2 = w1; off2 = 0; }
    } else {
      if (l < 2) { w2 = (grp + 2) * 32 + (lane - 32); off2 = -7; } // consumer guard
      else       { w2 = 6 * 32 + half; off2 = -7; }                // FC guard
    }
  } else {
    w1 = (4 + half) * 32 + (lane & 31); off1 = 1;                // h2(t) ready
    w2 = w1; off2 = 1;
  }

  const int arow = mf * 16 + l15;     // A row within the 64-row half
  const int kb = kh * 256;            // k-half base

  if (!isfc) {
    float biasr[4], creg[4];
#pragma unroll
    for (int n = 0; n < 4; ++n) biasr[n] = A.fbias[l * 2048 + n * 512 + c * 16 + l15];
#pragma unroll
    for (int q = 0; q < 4; ++q)
      creg[q] = A.c0[(size_t)l * 65536 + (half * 64 + mf * 16 + (l4 << 2) + q) * 512 + c * 16 + l15];
    __syncthreads();

    for (int t = 0; t < Tt; ++t) {
      if (tid < 64) wait2(flags, w1, t + off1, w2, t + off2);
      __syncthreads();

      const _Float16* hpv = A.hbuf + (size_t)(grp * 8 + ((t - 1) & 7)) * 32768
                            + arow * 512 + kb + (l4 << 2);
      f32x4 acc[4] = {};
      if (l == 0) {
        f16x4 a2[16];
        load_dc<16>(hpv, a2);                      // sc1 issued first
        f16x4 ax[3];
        const _Float16* xp = A.xb + ((size_t)(half * 64 + arow) * 512 + t) * 96
                             + kh * 48 + (l4 << 2);
#pragma unroll
        for (int i = 0; i < 3; ++i) ax[i] = *(const f16x4*)(xp + i * 16);
#pragma unroll
        for (int i = 0; i < 3; ++i)                // x-GEMM (linear [64][112] W_ih0)
#pragma unroll
          for (int n = 0; n < 4; ++n) {
            const int gr = n * 16 + l15;
            f16x4 bv = *(const f16x4*)(wlds + 32768 + gr * 112 + kh * 48 + i * 16 + (l4 << 2));
            acc[n] = __builtin_amdgcn_mfma_f32_16x16x16f16(ax[i], bv, acc[n], 0, 0, 0);
          }
        mma_swz<16, 4>(a2, wlds, kb, l15, l4, acc);
      } else {
        const _Float16* hin = A.hbuf + (size_t)((grp - 2) * 8 + (t & 7)) * 32768
                              + arow * 512 + kb + (l4 << 2);
        f16x4 a1[16], a2[16];
        load_dc<16>(hin, a1);
        load_dc<16>(hpv, a2);
        mma_swz<16, 4>(a1, wlds + 32768, kb, l15, l4, acc);
        mma_swz<16, 4>(a2, wlds, kb, l15, l4, acc);
      }

      if (kh == 1) {
#pragma unroll
        for (int n = 0; n < 4; ++n)
          *(f32x4*)&redx[(mf * 4 + n) * 256 + l15 * 16 + (l4 << 2)] = acc[n];
      }
      __syncthreads();
      if (kh == 0) {
#pragma unroll
        for (int n = 0; n < 4; ++n)
          acc[n] += *(const f32x4*)&redx[(mf * 4 + n) * 256 + l15 * 16 + (l4 << 2)];
        _Float16* rp = A.hbuf + (size_t)(grp * 8 + (t & 7)) * 32768;
#pragma unroll
        for (int q = 0; q < 4; ++q) {
          const int bl = mf * 16 + (l4 << 2) + q;
          float gi = acc[0][q] + biasr[0];
          float gf = acc[1][q] + biasr[1];
          float gg = acc[2][q] + biasr[2];
          float go = acc[3][q] + biasr[3];
          float iv = sigf(gi), fv = sigf(gf), gv = tanhf(gg), ov = sigf(go);
          float cn = fv * creg[q] + iv * gv;
          creg[q] = cn;
          float hv = ov * tanhf(cn);
          union { _Float16 h; unsigned short u; } cvt; cvt.h = (_Float16)hv;
          unsigned hb = cvt.u, ob = (unsigned)__shfl_xor((int)hb, 1, 64);
          if ((l15 & 1) == 0)
            st_dc_u32((unsigned*)(rp + bl * 512 + c * 16 + l15), hb | (ob << 16));
          if (t == Tt - 1) {
            A.out[OUT_H + (l * Bb + half * 64 + bl) * 512 + c * 16 + l15] = hv;
            A.out[OUT_C + (l * Bb + half * 64 + bl) * 512 + c * 16 + l15] = cn;
          }
        }
      }
      __syncthreads();   // drains vmcnt: sc1 h-stores at MALL before publish
      if (tid == 0) st_dc_u32(&flags[grp * 32 + c], (unsigned)(t + 1));
    }
  } else {
    float biasr[6];
#pragma unroll
    for (int n = 0; n < 6; ++n) biasr[n] = A.fbias[6144 + n * 16 + l15];
    __syncthreads();

    for (int t = 0; t < Tt; ++t) {
      if (tid < 64) wait2(flags, w1, t + off1, w2, t + off2);
      __syncthreads();

      const _Float16* hv2 = A.hbuf + (size_t)((4 + half) * 8 + (t & 7)) * 32768
                            + arow * 512 + kb + (l4 << 2);
      f16x4 a1[16];
      load_dc<16>(hv2, a1);
      f32x4 acc[6] = {};
      mma_swz<16, 6>(a1, wlds, kb, l15, l4, acc);

      if (kh == 1) {
#pragma unroll
        for (int n = 0; n < 6; ++n)
          *(f32x4*)&redx[(mf * 6 + n) * 256 + l15 * 16 + (l4 << 2)] = acc[n];
      }
      __syncthreads();
      if (kh == 0) {
#pragma unroll
        for (int n = 0; n < 6; ++n)
          acc[n] += *(const f32x4*)&redx[(mf * 6 + n) * 256 + l15 * 16 + (l4 << 2)];
#pragma unroll
        for (int q = 0; q < 4; ++q) {
          const int b = half * 64 + mf * 16 + (l4 << 2) + q;
#pragma unroll
          for (int n = 0; n < 6; ++n)
            A.out[((size_t)b * 512 + t) * 96 + n * 16 + l15] = acc[n][q] + biasr[n];
        }
      }
      __syncthreads();
      if (tid == 0) st_dc_u32(&flags[6 * 32 + half], (unsigned)(t + 1));
    }
  }
}

extern "C" void kernel_launch(void* const* d_in, const int* in_sizes, int n_in,
                              void* d_out, int out_size, void* d_ws, size_t ws_size,
                              hipStream_t stream) {
  char* base = (char*)d_ws;
  KP a;
  a.x    = (const float*)d_in[0];
  a.h0   = (const float*)d_in[1];
  a.c0   = (const float*)d_in[2];
  a.Wih0 = (const float*)d_in[3];  a.Whh0 = (const float*)d_in[4];
  a.bih0 = (const float*)d_in[5];  a.bhh0 = (const float*)d_in[6];
  a.Wih1 = (const float*)d_in[7];  a.Whh1 = (const float*)d_in[8];
  a.bih1 = (const float*)d_in[9];  a.bhh1 = (const float*)d_in[10];
  a.Wih2 = (const float*)d_in[11]; a.Whh2 = (const float*)d_in[12];
  a.bih2 = (const float*)d_in[13]; a.bhh2 = (const float*)d_in[14];
  a.Wfc  = (const float*)d_in[15]; a.bfc  = (const float*)d_in[16];
  a.out  = (float*)d_out;
  a.flags = (unsigned*)base;                     // 1 KB (7 groups x 128B lines)
  a.fbias = (float*)(base + 1024);               // 24,960 B
  a.wimg  = (_Float16*)(base + 26624);           // 12,582,912 B
  a.wfc   = (_Float16*)(base + 12609536);        // 98,304 B
  a.xb    = (_Float16*)(base + 12707840);        // 12,582,912 B
  a.hbuf  = (_Float16*)(base + 25290752);        // 3,145,728 B  (total ~28.4 MB)

  hipMemsetAsync(a.flags, 0, 1024, stream);
  hipLaunchKernelGGL(prologue_kernel, dim3(98), dim3(256), 0, stream, a);
  hipLaunchKernelGGL(lstm_persist, dim3(194), dim3(512), 0, stream, a);
}

// Round 9
// 5765.551 us; speedup vs baseline: 2.2273x; 1.1958x over previous
//
#include <hip/hip_runtime.h>

#define Bb 128
#define Tt 512
#define Vv 96
#define Hh 512
#define OUT_H 6291456
#define OUT_C 6488064

typedef _Float16 f16x4 __attribute__((ext_vector_type(4)));
typedef _Float16 f16x8 __attribute__((ext_vector_type(8)));
typedef float f32x4 __attribute__((ext_vector_type(4)));

struct KP {
  const float *x, *h0, *c0;
  const float *Wih0, *Whh0, *bih0, *bhh0;
  const float *Wih1, *Whh1, *bih1, *bhh1;
  const float *Wih2, *Whh2, *bih2, *bhh2;
  const float *Wfc, *bfc;
  float* out;
  unsigned* flags;   // [7 groups][32 words]: 1 cacheline per subgroup, single writer/word
  float* fbias;      // [3][2048] gate biases + [96] fc bias
  _Float16* wimg;    // [96][65536] cell weight images (W_hh | W_ih), pre-swizzled
  _Float16* wfc;     // [49152] FC weight image, pre-swizzled
  _Float16* xb;      // [128][512][96] f16 input
  _Float16* hbuf;    // [6 grp][32 slots][64][512] f16 h ring (write-once per slot/period)
};

__device__ __forceinline__ float sigf(float x) { return 1.f / (1.f + __expf(-x)); }

__device__ __forceinline__ void st_dc_u32(unsigned* p, unsigned v) {
  __hip_atomic_store(p, v, __ATOMIC_RELAXED, __HIP_MEMORY_SCOPE_AGENT);
}

// Dual wait: lane-private (word,target) pairs; sc1 polls with backoff after 64 iters.
__device__ __forceinline__ void wait2(unsigned* flags, int w1, int t1, int w2, int t2) {
  unsigned* p1 = flags + w1;
  unsigned* p2 = flags + w2;
  int g = 0;
  for (;;) {
    int v1 = (int)__hip_atomic_load(p1, __ATOMIC_RELAXED, __HIP_MEMORY_SCOPE_AGENT);
    int v2 = (int)__hip_atomic_load(p2, __ATOMIC_RELAXED, __HIP_MEMORY_SCOPE_AGENT);
    if (__all(v1 >= t1 && v2 >= t2)) break;
    if (++g > 30000) break;   // deadlock terminates; absmax diagnoses
    if (g < 64) __builtin_amdgcn_s_sleep(2);
    else        __builtin_amdgcn_s_sleep(8);
  }
}

// Plain cached loads (L1/L2). Safe: h slots are write-once per 32-step period;
// producer writes are sc1 (MALL), consumer cache turnover >> ring period.
template <int KS>
__device__ __forceinline__ void load_pl(const _Float16* __restrict__ p, f16x4 (&av)[KS]) {
#pragma unroll
  for (int i = 0; i < KS; ++i) av[i] = *(const f16x4*)(p + i * 16);
}

// acc += av (KS k-steps from k-base kb) * W^T from swizzled LDS [NF*16 rows][512].
template <int KS, int NF>
__device__ __forceinline__ void mma_swz(const f16x4 (&av)[KS], const _Float16* ldsb,
                                        int kb, int l15, int l4, f32x4 (&acc)[NF]) {
#pragma unroll
  for (int i = 0; i < KS; ++i) {
#pragma unroll
    for (int n = 0; n < NF; ++n) {
      const int gr = n * 16 + l15;
      const int idx = ((gr << 9) + kb + i * 16 + (l4 << 2)) ^ ((gr & 7) << 3);
      f16x4 bv = *(const f16x4*)(ldsb + idx);
      acc[n] = __builtin_amdgcn_mfma_f32_16x16x16f16(av[i], bv, acc[n], 0, 0, 0);
    }
  }
}

__global__ __launch_bounds__(256) void prologue_kernel(KP A) {
  const int tid = threadIdx.x, bid = blockIdx.x;
  const int gt = bid * 256 + tid, gn = 98 * 256;
  for (int i = gt; i < Bb * Tt * Vv; i += gn) A.xb[i] = (_Float16)A.x[i];
  // h0 -> hbuf slot 31 of each (l,half)
  for (int i = gt; i < 3 * Bb * Hh; i += gn) {
    int l = i >> 16, b = (i >> 9) & 127, col = i & 511;
    int half = b >> 6, bl = b & 63;
    A.hbuf[(size_t)((l * 2 + half) * 32 + 31) * 32768 + bl * 512 + col] = (_Float16)A.h0[i];
  }
  for (int i = gt; i < 3 * 2048; i += gn) {
    int l = i >> 11, cc = i & 2047;
    const float* bi = (l == 0) ? A.bih0 : (l == 1) ? A.bih1 : A.bih2;
    const float* bh = (l == 0) ? A.bhh0 : (l == 1) ? A.bhh1 : A.bhh2;
    A.fbias[i] = bi[cc] + bh[cc];
  }
  for (int i = gt; i < Vv; i += gn) A.fbias[3 * 2048 + i] = A.bfc[i];

  if (bid < 96) {
    const int l = bid >> 5, c = bid & 31;
    _Float16* img = A.wimg + (size_t)bid * 65536;
    const float* Wh = (l == 0) ? A.Whh0 : (l == 1) ? A.Whh1 : A.Whh2;
    for (int e = tid; e < 64 * 512; e += 256) {   // W_hh slice rows r = g*16+jj
      int r = e >> 9, k = e & 511;
      float v = Wh[((r >> 4) * 512 + c * 16 + (r & 15)) * Hh + k];
      img[(r * 512 + k) ^ ((r & 7) << 3)] = (_Float16)v;
    }
    if (l == 0) {
      for (int e = tid; e < 64 * 96; e += 256) {  // W_ih0 [64][112] padded, linear
        int r = e / 96, k = e - r * 96;
        img[32768 + r * 112 + k] = (_Float16)A.Wih0[((r >> 4) * 512 + c * 16 + (r & 15)) * Vv + k];
      }
    } else {
      const float* Wi = (l == 1) ? A.Wih1 : A.Wih2;
      for (int e = tid; e < 64 * 512; e += 256) {
        int r = e >> 9, k = e & 511;
        float v = Wi[((r >> 4) * 512 + c * 16 + (r & 15)) * Hh + k];
        img[32768 + ((r * 512 + k) ^ ((r & 7) << 3))] = (_Float16)v;
      }
    }
  } else {   // bid 96/97: FC image halves
    const int r0 = (bid - 96) * 48;
    for (int e = tid; e < 48 * 512; e += 256) {
      int r = r0 + (e >> 9), k = e & 511;
      A.wfc[(r * 512 + k) ^ ((r & 7) << 3)] = (_Float16)A.Wfc[r * 512 + k];
    }
  }
}

__global__ __launch_bounds__(512, 2) void lstm_persist(KP A) {
  __shared__ _Float16 wlds[65536];   // 128 KB weights
  __shared__ float redx[6144];       // 24 KB k-split reduction scratch
  const int tid = threadIdx.x, bid = blockIdx.x;
  const int lane = tid & 63, w = tid >> 6;
  const int l15 = lane & 15, l4 = lane >> 4;
  const int mf = w & 3, kh = w >> 2;
  unsigned* flags = A.flags;

  // one-time acquire: invalidate any pre-kernel L1/L2 lines for this CU's caches
  __builtin_amdgcn_fence(__ATOMIC_ACQUIRE, "agent");

  const bool isfc = (bid >= 192);
  const int l = isfc ? 2 : (bid >> 6);
  const int half = isfc ? (bid - 192) : ((bid >> 5) & 1);
  const int c = isfc ? 0 : (bid & 31);
  const int grp = isfc ? 6 : (l * 2 + half);

  {  // stage pre-swizzled weights once
    const f16x8* src = isfc ? (const f16x8*)A.wfc
                            : (const f16x8*)(A.wimg + (size_t)(l * 32 + c) * 65536);
    f16x8* dst = (f16x8*)wlds;
    const int cnt = isfc ? 6144 : 8192;
    for (int e = tid; e < cnt; e += 512) dst[e] = src[e];
  }

  // wait-set wiring: lane-private (word, target-offset) pairs
  int w1, w2, off1, off2;
  if (!isfc) {
    w1 = grp * 32 + (lane & 31); off1 = 0;                       // own subgroup >= t
    if (lane < 32) {
      if (l > 0) { w2 = (grp - 2) * 32 + lane; off2 = 1; }       // producer >= t+1
      else       { w2 = w1; off2 = 0; }
    } else {
      if (l < 2) { w2 = (grp + 2) * 32 + (lane - 32); off2 = -31; } // consumer guard
      else       { w2 = 6 * 32 + half; off2 = -31; }                // FC guard
    }
  } else {
    w1 = (4 + half) * 32 + (lane & 31); off1 = 1;                // h2(t) ready
    w2 = w1; off2 = 1;
  }

  const int arow = mf * 16 + l15;     // A row within the 64-row half
  const int kb = kh * 256;            // k-half base

  if (!isfc) {
    float biasr[4], creg[4];
#pragma unroll
    for (int n = 0; n < 4; ++n) biasr[n] = A.fbias[l * 2048 + n * 512 + c * 16 + l15];
#pragma unroll
    for (int q = 0; q < 4; ++q)
      creg[q] = A.c0[(size_t)l * 65536 + (half * 64 + mf * 16 + (l4 << 2) + q) * 512 + c * 16 + l15];
    __syncthreads();

    for (int t = 0; t < Tt; ++t) {
      if (tid < 64) wait2(flags, w1, t + off1, w2, t + off2);
      __syncthreads();

      const _Float16* hpv = A.hbuf + (size_t)(grp * 32 + ((t - 1) & 31)) * 32768
                            + arow * 512 + kb + (l4 << 2);
      f32x4 acc[4] = {};
      if (l == 0) {
        f16x4 a2[16];
        load_pl<16>(hpv, a2);                      // cached h loads issued first
        f16x4 ax[3];
        const _Float16* xp = A.xb + ((size_t)(half * 64 + arow) * 512 + t) * 96
                             + kh * 48 + (l4 << 2);
#pragma unroll
        for (int i = 0; i < 3; ++i) ax[i] = *(const f16x4*)(xp + i * 16);
#pragma unroll
        for (int i = 0; i < 3; ++i)                // x-GEMM (linear [64][112] W_ih0)
#pragma unroll
          for (int n = 0; n < 4; ++n) {
            const int gr = n * 16 + l15;
            f16x4 bv = *(const f16x4*)(wlds + 32768 + gr * 112 + kh * 48 + i * 16 + (l4 << 2));
            acc[n] = __builtin_amdgcn_mfma_f32_16x16x16f16(ax[i], bv, acc[n], 0, 0, 0);
          }
        mma_swz<16, 4>(a2, wlds, kb, l15, l4, acc);
      } else {
        const _Float16* hin = A.hbuf + (size_t)((grp - 2) * 32 + (t & 31)) * 32768
                              + arow * 512 + kb + (l4 << 2);
        f16x4 a1[16], a2[16];
        load_pl<16>(hin, a1);
        load_pl<16>(hpv, a2);
        mma_swz<16, 4>(a1, wlds + 32768, kb, l15, l4, acc);
        mma_swz<16, 4>(a2, wlds, kb, l15, l4, acc);
      }

      if (kh == 1) {
#pragma unroll
        for (int n = 0; n < 4; ++n)
          *(f32x4*)&redx[(mf * 4 + n) * 256 + l15 * 16 + (l4 << 2)] = acc[n];
      }
      __syncthreads();
      if (kh == 0) {
#pragma unroll
        for (int n = 0; n < 4; ++n)
          acc[n] += *(const f32x4*)&redx[(mf * 4 + n) * 256 + l15 * 16 + (l4 << 2)];
        _Float16* rp = A.hbuf + (size_t)(grp * 32 + (t & 31)) * 32768;
#pragma unroll
        for (int q = 0; q < 4; ++q) {
          const int bl = mf * 16 + (l4 << 2) + q;
          float gi = acc[0][q] + biasr[0];
          float gf = acc[1][q] + biasr[1];
          float gg = acc[2][q] + biasr[2];
          float go = acc[3][q] + biasr[3];
          float iv = sigf(gi), fv = sigf(gf), gv = tanhf(gg), ov = sigf(go);
          float cn = fv * creg[q] + iv * gv;
          creg[q] = cn;
          float hv = ov * tanhf(cn);
          union { _Float16 h; unsigned short u; } cvt; cvt.h = (_Float16)hv;
          unsigned hb = cvt.u, ob = (unsigned)__shfl_xor((int)hb, 1, 64);
          if ((l15 & 1) == 0)
            st_dc_u32((unsigned*)(rp + bl * 512 + c * 16 + l15), hb | (ob << 16));
          if (t == Tt - 1) {
            A.out[OUT_H + (l * Bb + half * 64 + bl) * 512 + c * 16 + l15] = hv;
            A.out[OUT_C + (l * Bb + half * 64 + bl) * 512 + c * 16 + l15] = cn;
          }
        }
      }
      __syncthreads();   // drains vmcnt: sc1 h-stores at MALL before publish
      if (tid == 0) st_dc_u32(&flags[grp * 32 + c], (unsigned)(t + 1));
    }
  } else {
    float biasr[6];
#pragma unroll
    for (int n = 0; n < 6; ++n) biasr[n] = A.fbias[6144 + n * 16 + l15];
    __syncthreads();

    for (int t = 0; t < Tt; ++t) {
      if (tid < 64) wait2(flags, w1, t + off1, w2, t + off2);
      __syncthreads();

      const _Float16* hv2 = A.hbuf + (size_t)((4 + half) * 32 + (t & 31)) * 32768
                            + arow * 512 + kb + (l4 << 2);
      f16x4 a1[16];
      load_pl<16>(hv2, a1);
      f32x4 acc[6] = {};
      mma_swz<16, 6>(a1, wlds, kb, l15, l4, acc);

      if (kh == 1) {
#pragma unroll
        for (int n = 0; n < 6; ++n)
          *(f32x4*)&redx[(mf * 6 + n) * 256 + l15 * 16 + (l4 << 2)] = acc[n];
      }
      __syncthreads();
      if (kh == 0) {
#pragma unroll
        for (int n = 0; n < 6; ++n)
          acc[n] += *(const f32x4*)&redx[(mf * 6 + n) * 256 + l15 * 16 + (l4 << 2)];
#pragma unroll
        for (int q = 0; q < 4; ++q) {
          const int b = half * 64 + mf * 16 + (l4 << 2) + q;
#pragma unroll
          for (int n = 0; n < 6; ++n)
            A.out[((size_t)b * 512 + t) * 96 + n * 16 + l15] = acc[n][q] + biasr[n];
        }
      }
      __syncthreads();
      if (tid == 0) st_dc_u32(&flags[6 * 32 + half], (unsigned)(t + 1));
    }
  }
}

extern "C" void kernel_launch(void* const* d_in, const int* in_sizes, int n_in,
                              void* d_out, int out_size, void* d_ws, size_t ws_size,
                              hipStream_t stream) {
  char* base = (char*)d_ws;
  KP a;
  a.x    = (const float*)d_in[0];
  a.h0   = (const float*)d_in[1];
  a.c0   = (const float*)d_in[2];
  a.Wih0 = (const float*)d_in[3];  a.Whh0 = (const float*)d_in[4];
  a.bih0 = (const float*)d_in[5];  a.bhh0 = (const float*)d_in[6];
  a.Wih1 = (const float*)d_in[7];  a.Whh1 = (const float*)d_in[8];
  a.bih1 = (const float*)d_in[9];  a.bhh1 = (const float*)d_in[10];
  a.Wih2 = (const float*)d_in[11]; a.Whh2 = (const float*)d_in[12];
  a.bih2 = (const float*)d_in[13]; a.bhh2 = (const float*)d_in[14];
  a.Wfc  = (const float*)d_in[15]; a.bfc  = (const float*)d_in[16];
  a.out  = (float*)d_out;
  a.flags = (unsigned*)base;                     // 1 KB (7 groups x 128B lines)
  a.fbias = (float*)(base + 1024);               // 24,960 B
  a.wimg  = (_Float16*)(base + 26624);           // 12,582,912 B
  a.wfc   = (_Float16*)(base + 12609536);        // 98,304 B
  a.xb    = (_Float16*)(base + 12707840);        // 12,582,912 B
  a.hbuf  = (_Float16*)(base + 25290752);        // 12,582,912 B  (total ~37.9 MB)

  hipError_t err = hipMemsetAsync(a.flags, 0, 1024, stream);
  (void)err;
  hipLaunchKernelGGL(prologue_kernel, dim3(98), dim3(256), 0, stream, a);
  hipLaunchKernelGGL(lstm_persist, dim3(194), dim3(512), 0, stream, a);
}